// Round 1
// baseline (698.409 us; speedup 1.0000x reference)
//
#include <hip/hip_runtime.h>
#include <hip/hip_bf16.h>

#define NS 65536
#define NQ 131072
#define DD 256
#define NC 1024

typedef __attribute__((ext_vector_type(8))) short short8;
typedef __attribute__((ext_vector_type(4))) float f32x4;

static __device__ __forceinline__ unsigned short f2bf(float f) {
    unsigned int u = __float_as_uint(f);
    u += 0x7fffu + ((u >> 16) & 1u);          // round-to-nearest-even
    return (unsigned short)(u >> 16);
}

// K1: normalize each support row, atomically scatter into per-class sums + counts
__global__ __launch_bounds__(256) void k_scatter(const float* __restrict__ sf,
                                                 const int* __restrict__ labels,
                                                 float* __restrict__ sums,
                                                 float* __restrict__ counts) {
    const int row  = (blockIdx.x << 2) + (threadIdx.x >> 6);
    const int lane = threadIdx.x & 63;
    float4 v = *reinterpret_cast<const float4*>(sf + (size_t)row * DD + lane * 4);
    float ss = v.x*v.x + v.y*v.y + v.z*v.z + v.w*v.w;
#pragma unroll
    for (int off = 32; off; off >>= 1) ss += __shfl_xor(ss, off);
    const float r = 1.0f / fmaxf(sqrtf(ss), 1e-8f);
    const int lab = labels[row];
    float* dst = sums + (size_t)lab * DD + lane * 4;
    atomicAdd(dst + 0, v.x * r);
    atomicAdd(dst + 1, v.y * r);
    atomicAdd(dst + 2, v.z * r);
    atomicAdd(dst + 3, v.w * r);
    if (lane == 0) atomicAdd(counts + lab, 1.0f);
}

// K2: prototypes = l2norm(sums / max(cnt,1)) -> bf16 [NC][DD]; also write arange tail
__global__ __launch_bounds__(256) void k_proto(const float* __restrict__ sums,
                                               const float* __restrict__ counts,
                                               unsigned short* __restrict__ pb,
                                               float* __restrict__ outTail) {
    const int c = blockIdx.x;
    const int t = threadIdx.x;
    const float cnt = fmaxf(counts[c], 1.0f);
    const float m = sums[(size_t)c * DD + t] / cnt;
    float ss = m * m;
#pragma unroll
    for (int off = 32; off; off >>= 1) ss += __shfl_xor(ss, off);
    __shared__ float red[4];
    if ((t & 63) == 0) red[t >> 6] = ss;
    __syncthreads();
    const float tot = red[0] + red[1] + red[2] + red[3];
    const float r = 1.0f / fmaxf(sqrtf(tot), 1e-8f);
    pb[(size_t)c * DD + t] = f2bf(m * r);
    if (t == 0) outTail[c] = (float)c;
}

// K3: fused GEMM (bf16 MFMA 16x16x32) + qnorm scaling + row log_softmax.
// Block: 512 threads = 8 waves. BM=32 query rows, each wave owns 128 of 1024 cols.
__global__ __launch_bounds__(512) void k_gemm_lsm(const float* __restrict__ qf,
                                                  const unsigned short* __restrict__ pb,
                                                  float* __restrict__ out) {
    __shared__ float qinvLds[32];
    __shared__ float red[32][8];
    __shared__ float rowM[32];
    __shared__ float rowL[32];

    const int tid  = threadIdx.x;
    const int w    = tid >> 6;
    const int lane = tid & 63;
    const int g    = lane >> 4;
    const int r16  = lane & 15;
    const size_t qbase = (size_t)blockIdx.x * 32;

    f32x4 acc[2][8];
#pragma unroll
    for (int m = 0; m < 2; ++m)
#pragma unroll
        for (int n = 0; n < 8; ++n) acc[m][n] = (f32x4){0.f, 0.f, 0.f, 0.f};

    const float* qrow0 = qf + (qbase + r16) * DD;
    const float* qrow1 = qf + (qbase + 16 + r16) * DD;
    const unsigned short* pcol = pb + (size_t)(w * 128 + r16) * DD;

    float ss0 = 0.f, ss1 = 0.f;
#pragma unroll
    for (int kk = 0; kk < 8; ++kk) {
        const int kb = kk * 32 + g * 8;
        float4 a00 = *reinterpret_cast<const float4*>(qrow0 + kb);
        float4 a01 = *reinterpret_cast<const float4*>(qrow0 + kb + 4);
        float4 a10 = *reinterpret_cast<const float4*>(qrow1 + kb);
        float4 a11 = *reinterpret_cast<const float4*>(qrow1 + kb + 4);
        ss0 += a00.x*a00.x + a00.y*a00.y + a00.z*a00.z + a00.w*a00.w
             + a01.x*a01.x + a01.y*a01.y + a01.z*a01.z + a01.w*a01.w;
        ss1 += a10.x*a10.x + a10.y*a10.y + a10.z*a10.z + a10.w*a10.w
             + a11.x*a11.x + a11.y*a11.y + a11.z*a11.z + a11.w*a11.w;
        short8 a0, a1;
        a0[0] = (short)f2bf(a00.x); a0[1] = (short)f2bf(a00.y);
        a0[2] = (short)f2bf(a00.z); a0[3] = (short)f2bf(a00.w);
        a0[4] = (short)f2bf(a01.x); a0[5] = (short)f2bf(a01.y);
        a0[6] = (short)f2bf(a01.z); a0[7] = (short)f2bf(a01.w);
        a1[0] = (short)f2bf(a10.x); a1[1] = (short)f2bf(a10.y);
        a1[2] = (short)f2bf(a10.z); a1[3] = (short)f2bf(a10.w);
        a1[4] = (short)f2bf(a11.x); a1[5] = (short)f2bf(a11.y);
        a1[6] = (short)f2bf(a11.z); a1[7] = (short)f2bf(a11.w);
#pragma unroll
        for (int n = 0; n < 8; ++n) {
            short8 b = *reinterpret_cast<const short8*>(pcol + (size_t)n * 16 * DD + kb);
            acc[0][n] = __builtin_amdgcn_mfma_f32_16x16x32_bf16(a0, b, acc[0][n], 0, 0, 0);
            acc[1][n] = __builtin_amdgcn_mfma_f32_16x16x32_bf16(a1, b, acc[1][n], 0, 0, 0);
        }
    }

    // complete per-row sumsq: lane holds partial for row r16 over its k-segments; sum over g
    ss0 += __shfl_xor(ss0, 16); ss0 += __shfl_xor(ss0, 32);
    ss1 += __shfl_xor(ss1, 16); ss1 += __shfl_xor(ss1, 32);
    if (w == 0 && lane < 16) {
        qinvLds[lane]      = 1.0f / fmaxf(sqrtf(ss0), 1e-8f);
        qinvLds[16 + lane] = 1.0f / fmaxf(sqrtf(ss1), 1e-8f);
    }
    __syncthreads();

    float qi[2][4];
#pragma unroll
    for (int m = 0; m < 2; ++m)
#pragma unroll
        for (int j = 0; j < 4; ++j) qi[m][j] = qinvLds[m * 16 + g * 4 + j];

#pragma unroll
    for (int m = 0; m < 2; ++m)
#pragma unroll
        for (int n = 0; n < 8; ++n)
#pragma unroll
            for (int j = 0; j < 4; ++j) acc[m][n][j] *= qi[m][j];

    // per-row max: over this wave's 8 col-frags, then across the 16 lanes of the group
    float rmax[2][4];
#pragma unroll
    for (int m = 0; m < 2; ++m)
#pragma unroll
        for (int j = 0; j < 4; ++j) {
            float v = acc[m][0][j];
#pragma unroll
            for (int n = 1; n < 8; ++n) v = fmaxf(v, acc[m][n][j]);
#pragma unroll
            for (int off = 1; off < 16; off <<= 1) v = fmaxf(v, __shfl_xor(v, off));
            rmax[m][j] = v;
        }
    if (r16 == 0) {
#pragma unroll
        for (int m = 0; m < 2; ++m)
#pragma unroll
            for (int j = 0; j < 4; ++j) red[m * 16 + g * 4 + j][w] = rmax[m][j];
    }
    __syncthreads();
    if (tid < 32) {
        float v = red[tid][0];
#pragma unroll
        for (int k = 1; k < 8; ++k) v = fmaxf(v, red[tid][k]);
        rowM[tid] = v;
    }
    __syncthreads();

    // per-row sum of exp
    float rsum[2][4];
#pragma unroll
    for (int m = 0; m < 2; ++m)
#pragma unroll
        for (int j = 0; j < 4; ++j) {
            const float rm = rowM[m * 16 + g * 4 + j];
            float s = 0.f;
#pragma unroll
            for (int n = 0; n < 8; ++n) s += __expf(acc[m][n][j] - rm);
#pragma unroll
            for (int off = 1; off < 16; off <<= 1) s += __shfl_xor(s, off);
            rsum[m][j] = s;
        }
    if (r16 == 0) {
#pragma unroll
        for (int m = 0; m < 2; ++m)
#pragma unroll
            for (int j = 0; j < 4; ++j) red[m * 16 + g * 4 + j][w] = rsum[m][j];
    }
    __syncthreads();
    if (tid < 32) {
        float s = red[tid][0];
#pragma unroll
        for (int k = 1; k < 8; ++k) s += red[tid][k];
        rowL[tid] = rowM[tid] + __logf(s);
    }
    __syncthreads();

    // write log_probs
#pragma unroll
    for (int m = 0; m < 2; ++m)
#pragma unroll
        for (int j = 0; j < 4; ++j) {
            const float sub = rowL[m * 16 + g * 4 + j];
            float* orow = out + (qbase + m * 16 + g * 4 + j) * (size_t)NC + w * 128 + r16;
#pragma unroll
            for (int n = 0; n < 8; ++n) orow[n * 16] = acc[m][n][j] - sub;
        }
}

extern "C" void kernel_launch(void* const* d_in, const int* in_sizes, int n_in,
                              void* d_out, int out_size, void* d_ws, size_t ws_size,
                              hipStream_t stream) {
    const float* sf     = (const float*)d_in[0];
    const int*   labels = (const int*)d_in[1];
    const float* qf     = (const float*)d_in[2];
    float* out = (float*)d_out;

    float* sums   = (float*)d_ws;                       // [NC][DD] f32, 1 MiB
    float* counts = sums + (size_t)NC * DD;             // [NC] f32
    unsigned short* pb = (unsigned short*)(counts + NC); // [NC][DD] bf16, 512 KiB

    hipMemsetAsync(d_ws, 0, ((size_t)NC * DD + NC) * sizeof(float), stream);

    k_scatter<<<NS / 4, 256, 0, stream>>>(sf, labels, sums, counts);

    float* outTail = out + (size_t)out_size - NC;       // unique_classes as floats
    k_proto<<<NC, 256, 0, stream>>>(sums, counts, pb, outTail);

    k_gemm_lsm<<<NQ / 32, 512, 0, stream>>>(qf, pb, out);
}

// Round 2
// 398.058 us; speedup vs baseline: 1.7545x; 1.7545x over previous
//
#include <hip/hip_runtime.h>
#include <hip/hip_bf16.h>

#define NS 65536
#define NQ 131072
#define DD 256
#define NC 1024
#define BM 32

typedef __attribute__((ext_vector_type(8))) short short8;
typedef __attribute__((ext_vector_type(4))) float f32x4;

// dynamic LDS carve (bytes)
#define SMEM_B0    0
#define SMEM_B1    65536
#define SMEM_A     131072
#define SMEM_QI    147456
#define SMEM_RED   147584
#define SMEM_ROWM  148608
#define SMEM_ROWL  148736
#define SMEM_TOTAL 148864

static __device__ __forceinline__ unsigned short f2bf(float f) {
    unsigned int u = __float_as_uint(f);
    u += 0x7fffu + ((u >> 16) & 1u);          // round-to-nearest-even
    return (unsigned short)(u >> 16);
}

// CK-style global->LDS direct copy, 16B per lane, LDS dest wave-uniform+lane*16
static __device__ __forceinline__ void gload_lds16(const void* src, void* dst) {
    using GPtr = const __attribute__((address_space(1))) unsigned int*;
    using LPtr = __attribute__((address_space(3))) unsigned int*;
    GPtr g = reinterpret_cast<GPtr>(reinterpret_cast<uintptr_t>(src));
    LPtr l = reinterpret_cast<LPtr>(static_cast<unsigned int>(reinterpret_cast<uintptr_t>(dst)));
    __builtin_amdgcn_global_load_lds(g, l, 16, 0, 0);
}

// K1a: per-row inverse L2 norm of support rows (one wave per row)
__global__ __launch_bounds__(256) void k_rinv(const float* __restrict__ sf,
                                              float* __restrict__ rinv) {
    const int row  = (blockIdx.x << 2) + (threadIdx.x >> 6);
    const int lane = threadIdx.x & 63;
    float4 v = *reinterpret_cast<const float4*>(sf + (size_t)row * DD + lane * 4);
    float ss = v.x*v.x + v.y*v.y + v.z*v.z + v.w*v.w;
#pragma unroll
    for (int off = 32; off; off >>= 1) ss += __shfl_xor(ss, off);
    if (lane == 0) rinv[row] = 1.0f / fmaxf(sqrtf(ss), 1e-8f);
}

// K1b: one block per class. Deterministic ballot-compacted row list per wave,
// then per-dim accumulation (thread t owns dim t). Produces bf16 prototypes
// and the arange tail. No global atomics, no ws zero-init needed.
__global__ __launch_bounds__(256) void k_proto(const float* __restrict__ sf,
                                               const int* __restrict__ labels,
                                               const float* __restrict__ rinv,
                                               unsigned short* __restrict__ pb,
                                               float* __restrict__ outTail) {
    __shared__ int lists[4][96];
    __shared__ int wcnts[4];
    __shared__ float red[4];
    const int c = blockIdx.x;
    const int t = threadIdx.x;
    const int w = t >> 6;
    const int lane = t & 63;

    int cnt = 0;
    const int base0 = w * (NS / 4);
    for (int i = 0; i < NS / 4; i += 64) {
        const int lab = labels[base0 + i + lane];
        const unsigned long long m = __ballot(lab == c);
        if (lab == c) {
            int pos = cnt + __popcll(m & ((1ull << lane) - 1ull));
            if (pos < 96) lists[w][pos] = base0 + i + lane;
        }
        cnt += (int)__popcll(m);
    }
    if (lane == 0) wcnts[w] = cnt;
    __syncthreads();

    float acc = 0.f;
    int total = 0;
    for (int ww = 0; ww < 4; ++ww) {
        const int n = min(wcnts[ww], 96);
        total += wcnts[ww];
        for (int j = 0; j < n; ++j) {
            const int row = lists[ww][j];
            acc += sf[(size_t)row * DD + t] * rinv[row];
        }
    }
    const float m = acc / fmaxf((float)total, 1.0f);
    float ss = m * m;
#pragma unroll
    for (int off = 32; off; off >>= 1) ss += __shfl_xor(ss, off);
    if ((t & 63) == 0) red[t >> 6] = ss;
    __syncthreads();
    const float tot = red[0] + red[1] + red[2] + red[3];
    const float r = 1.0f / fmaxf(sqrtf(tot), 1e-8f);
    pb[(size_t)c * DD + t] = f2bf(m * r);
    if (t == 0) outTail[c] = (float)c;
}

// stage one 128-col B tile (64 KB) into LDS buffer, source pre-swizzled so a
// swizzled ds_read is conflict-free (T2 both-sides rule).
static __device__ __forceinline__ void stageB(char* smem, const char* pbB,
                                              int w, int lane, int tile, int bufOff) {
#pragma unroll
    for (int i = 0; i < 8; ++i) {
        const int e = w * 512 + i * 64 + lane;       // 16B element index in tile
        const int col = e >> 5;                       // within-tile col 0..127
        const int chunk = e & 31;                     // 16B chunk within 512B row
        const char* src = pbB + ((size_t)(tile * 128 + col) << 9)
                              + (((chunk ^ (col & 7)) << 4));
        char* dst = smem + bufOff + w * 8192 + i * 1024;   // wave-uniform
        gload_lds16(src, dst);
    }
}

// K3: fused GEMM + qnorm + log_softmax. 512 thr = 8 waves, BM=32 rows/block,
// wave w owns n-frag w of each 128-col tile (cols t*128 + w*16 + r16).
__global__ __launch_bounds__(512, 2) void k_gemm_lsm(const float* __restrict__ qf,
                                                     const unsigned short* __restrict__ pb,
                                                     float* __restrict__ out) {
    extern __shared__ char smem[];
    const int tid  = threadIdx.x;
    const int w    = tid >> 6;
    const int lane = tid & 63;
    const int g    = lane >> 4;
    const int r16  = lane & 15;
    const size_t qbase = (size_t)blockIdx.x * BM;
    const char* pbB = (const char*)pb;

    // issue B tile 0 stage immediately (overlaps A staging below)
    stageB(smem, pbB, w, lane, 0, SMEM_B0);

    // A stage: thread t handles row t>>4, 16 floats at seg*16. Compute sumsq,
    // convert to bf16, swizzled ds_write.
    {
        const int row = tid >> 4;
        const int seg = tid & 15;
        const float* qrow = qf + (qbase + row) * (size_t)DD + seg * 16;
        float4 f0 = *reinterpret_cast<const float4*>(qrow + 0);
        float4 f1 = *reinterpret_cast<const float4*>(qrow + 4);
        float4 f2 = *reinterpret_cast<const float4*>(qrow + 8);
        float4 f3 = *reinterpret_cast<const float4*>(qrow + 12);
        float ss = f0.x*f0.x + f0.y*f0.y + f0.z*f0.z + f0.w*f0.w
                 + f1.x*f1.x + f1.y*f1.y + f1.z*f1.z + f1.w*f1.w
                 + f2.x*f2.x + f2.y*f2.y + f2.z*f2.z + f2.w*f2.w
                 + f3.x*f3.x + f3.y*f3.y + f3.z*f3.z + f3.w*f3.w;
        ss += __shfl_xor(ss, 1); ss += __shfl_xor(ss, 2);
        ss += __shfl_xor(ss, 4); ss += __shfl_xor(ss, 8);
        short8 h0, h1;
        h0[0]=(short)f2bf(f0.x); h0[1]=(short)f2bf(f0.y); h0[2]=(short)f2bf(f0.z); h0[3]=(short)f2bf(f0.w);
        h0[4]=(short)f2bf(f1.x); h0[5]=(short)f2bf(f1.y); h0[6]=(short)f2bf(f1.z); h0[7]=(short)f2bf(f1.w);
        h1[0]=(short)f2bf(f2.x); h1[1]=(short)f2bf(f2.y); h1[2]=(short)f2bf(f2.z); h1[3]=(short)f2bf(f2.w);
        h1[4]=(short)f2bf(f3.x); h1[5]=(short)f2bf(f3.y); h1[6]=(short)f2bf(f3.z); h1[7]=(short)f2bf(f3.w);
        const int x = row & 7;
        char* aRow = smem + SMEM_A + row * 512;
        *reinterpret_cast<short8*>(aRow + (((seg*2)     ^ x) << 4)) = h0;
        *reinterpret_cast<short8*>(aRow + (((seg*2 + 1) ^ x) << 4)) = h1;
        if (seg == 0)
            reinterpret_cast<float*>(smem + SMEM_QI)[row] = 1.0f / fmaxf(sqrtf(ss), 1e-8f);
    }
    __syncthreads();   // drains B tile0 (vmcnt) + A writes (lgkm)

    // hoist A frags: 16 b128 reads -> 64 VGPRs, reused for all 8 tiles
    short8 a[2][8];
#pragma unroll
    for (int m2 = 0; m2 < 2; ++m2)
#pragma unroll
        for (int kk = 0; kk < 8; ++kk) {
            const int row = m2 * 16 + r16;
            const int chunk = (kk * 4 + g) ^ (row & 7);
            a[m2][kk] = *reinterpret_cast<const short8*>(smem + SMEM_A + row * 512 + chunk * 16);
        }

    f32x4 acc[2][8];
#pragma unroll
    for (int m2 = 0; m2 < 2; ++m2)
#pragma unroll
        for (int n = 0; n < 8; ++n) acc[m2][n] = (f32x4){0.f, 0.f, 0.f, 0.f};

    const int colL = w * 16 + r16;        // within-tile B col
    const int bswz = colL & 7;

#pragma unroll
    for (int t = 0; t < 8; ++t) {
        if (t < 7) stageB(smem, pbB, w, lane, t + 1, ((t + 1) & 1) ? SMEM_B1 : SMEM_B0);
        const char* bBase = smem + ((t & 1) ? SMEM_B1 : SMEM_B0) + colL * 512;
#pragma unroll
        for (int kk = 0; kk < 8; ++kk) {
            short8 b = *reinterpret_cast<const short8*>(bBase + (((kk * 4 + g) ^ bswz) << 4));
            acc[0][t] = __builtin_amdgcn_mfma_f32_16x16x32_bf16(a[0][kk], b, acc[0][t], 0, 0, 0);
            acc[1][t] = __builtin_amdgcn_mfma_f32_16x16x32_bf16(a[1][kk], b, acc[1][t], 0, 0, 0);
        }
        __syncthreads();  // tile t reads done by all waves; tile t+1 staged (vmcnt drained)
    }

    // ---- epilogue: qinv scale + row log_softmax ----
    float* qinvLds = reinterpret_cast<float*>(smem + SMEM_QI);
    float (*red)[8] = reinterpret_cast<float(*)[8]>(smem + SMEM_RED);
    float* rowM = reinterpret_cast<float*>(smem + SMEM_ROWM);
    float* rowL = reinterpret_cast<float*>(smem + SMEM_ROWL);

    float qi[2][4];
#pragma unroll
    for (int m2 = 0; m2 < 2; ++m2)
#pragma unroll
        for (int j = 0; j < 4; ++j) qi[m2][j] = qinvLds[m2 * 16 + g * 4 + j];

#pragma unroll
    for (int m2 = 0; m2 < 2; ++m2)
#pragma unroll
        for (int n = 0; n < 8; ++n)
#pragma unroll
            for (int j = 0; j < 4; ++j) acc[m2][n][j] *= qi[m2][j];

    float rmax[2][4];
#pragma unroll
    for (int m2 = 0; m2 < 2; ++m2)
#pragma unroll
        for (int j = 0; j < 4; ++j) {
            float v = acc[m2][0][j];
#pragma unroll
            for (int n = 1; n < 8; ++n) v = fmaxf(v, acc[m2][n][j]);
#pragma unroll
            for (int off = 1; off < 16; off <<= 1) v = fmaxf(v, __shfl_xor(v, off));
            rmax[m2][j] = v;
        }
    if (r16 == 0) {
#pragma unroll
        for (int m2 = 0; m2 < 2; ++m2)
#pragma unroll
            for (int j = 0; j < 4; ++j) red[m2 * 16 + g * 4 + j][w] = rmax[m2][j];
    }
    __syncthreads();
    if (tid < 32) {
        float v = red[tid][0];
#pragma unroll
        for (int k = 1; k < 8; ++k) v = fmaxf(v, red[tid][k]);
        rowM[tid] = v;
    }
    __syncthreads();

    float rsum[2][4];
#pragma unroll
    for (int m2 = 0; m2 < 2; ++m2)
#pragma unroll
        for (int j = 0; j < 4; ++j) {
            const float rm = rowM[m2 * 16 + g * 4 + j];
            float s = 0.f;
#pragma unroll
            for (int n = 0; n < 8; ++n) s += __expf(acc[m2][n][j] - rm);
#pragma unroll
            for (int off = 1; off < 16; off <<= 1) s += __shfl_xor(s, off);
            rsum[m2][j] = s;
        }
    if (r16 == 0) {
#pragma unroll
        for (int m2 = 0; m2 < 2; ++m2)
#pragma unroll
            for (int j = 0; j < 4; ++j) red[m2 * 16 + g * 4 + j][w] = rsum[m2][j];
    }
    __syncthreads();
    if (tid < 32) {
        float s = red[tid][0];
#pragma unroll
        for (int k = 1; k < 8; ++k) s += red[tid][k];
        rowL[tid] = rowM[tid] + __logf(s);
    }
    __syncthreads();

#pragma unroll
    for (int m2 = 0; m2 < 2; ++m2)
#pragma unroll
        for (int j = 0; j < 4; ++j) {
            const float sub = rowL[m2 * 16 + g * 4 + j];
            float* orow = out + (qbase + m2 * 16 + g * 4 + j) * (size_t)NC + w * 16 + r16;
#pragma unroll
            for (int n = 0; n < 8; ++n) orow[n * 128] = acc[m2][n][j] - sub;
        }
}

extern "C" void kernel_launch(void* const* d_in, const int* in_sizes, int n_in,
                              void* d_out, int out_size, void* d_ws, size_t ws_size,
                              hipStream_t stream) {
    const float* sf     = (const float*)d_in[0];
    const int*   labels = (const int*)d_in[1];
    const float* qf     = (const float*)d_in[2];
    float* out = (float*)d_out;

    float* rinv = (float*)d_ws;                                   // 256 KiB
    unsigned short* pb = (unsigned short*)((char*)d_ws + (size_t)NS * 4);  // 512 KiB

    hipFuncSetAttribute(reinterpret_cast<const void*>(k_gemm_lsm),
                        hipFuncAttributeMaxDynamicSharedMemorySize, SMEM_TOTAL);

    k_rinv<<<NS / 4, 256, 0, stream>>>(sf, rinv);

    float* outTail = out + (size_t)out_size - NC;
    k_proto<<<NC, 256, 0, stream>>>(sf, labels, rinv, pb, outTail);

    k_gemm_lsm<<<NQ / BM, 512, SMEM_TOTAL, stream>>>(qf, pb, out);
}